// Round 5
// baseline (105.508 us; speedup 1.0000x reference)
//
#include <hip/hip_runtime.h>
#include <hip/hip_bf16.h>
#include <math.h>

#define HID 128
#define ATT 64
#define HOPS 8
#define T_ 64
#define N_ 64
#define B_ 64
#define L_ 4096

typedef __attribute__((ext_vector_type(8))) short bf16x8;
typedef __attribute__((ext_vector_type(4))) float f32x4;

static constexpr size_t OFF_A     = (size_t)B_ * N_ * T_;              // 262144
static constexpr size_t OFF_NEIGH = OFF_A + (size_t)B_ * HOPS * L_;    // 2359296
static constexpr size_t OFF_PENAL = OFF_NEIGH + (size_t)B_ * L_ * HID; // 35913728

__device__ __forceinline__ unsigned pkbf(float lo, float hi) {
    unsigned a = (unsigned)(unsigned short)__builtin_bit_cast(unsigned short, __float2bfloat16(lo));
    unsigned b = (unsigned)(unsigned short)__builtin_bit_cast(unsigned short, __float2bfloat16(hi));
    return a | (b << 16);
}
__device__ __forceinline__ short f2bf(float x) {
    return __builtin_bit_cast(short, __float2bfloat16(x));
}

// ---------------- K1: linear-coalesced staging + MFMA s1->tanh->s2 -------------------
// Block = one 64-row tile (grid 4096). Phase A: linear float4 streams (load neigh,
// store copy), H=neigh*node packed bf16 -> LDS (stride 68 u32: uniform bank tiling
// for ds_read_b128). Phase B: per-wave 16-row MFMA s1 GEMM, tanh, s2 MFMA.
__global__ __launch_bounds__(256, 3)
void k1_mfma(const float* __restrict__ node, const float* __restrict__ neigh,
             const int* __restrict__ nnum, const float* __restrict__ W1,
             const float* __restrict__ b1, const float* __restrict__ W2,
             const float* __restrict__ b2, float* __restrict__ out)
{
    __shared__ __align__(16) unsigned w1lds[64 * 68];   // W1 bf16 pairs [a][kp], stride 68 u32
    __shared__ __align__(16) unsigned hlds [64 * 68];   // H  bf16 pairs [row][kp], stride 68 u32
    __shared__ __align__(16) short    thlds[4][16 * 72];// per-wave tanh tile, stride 72 shorts

    const int tid  = threadIdx.x;
    const int b    = blockIdx.x >> 6;
    const int tile = blockIdx.x & 63;

    const size_t base = ((size_t)b * L_ + (size_t)tile * 64) * HID;
    const float* nb  = neigh + base;
    float*       cb  = out + OFF_NEIGH + base;
    const float* ndb = node + (size_t)b * T_ * HID;
    float*       s2base = out + OFF_A + (size_t)b * HOPS * L_;

    // ---- phase A: issue all tile loads first (linear, coalesced), then fan out ----
    float4 v[8], nv[8];
    #pragma unroll
    for (int r = 0; r < 8; ++r)
        v[r] = *(const float4*)(nb + r * 1024 + tid * 4);
    const int arow0 = tid >> 5;            // 0..7
    const int acol  = (tid * 4) & 127;
    #pragma unroll
    for (int r = 0; r < 8; ++r)
        nv[r] = *(const float4*)(ndb + (r * 8 + arow0) * HID + acol);
    #pragma unroll
    for (int r = 0; r < 8; ++r) {
        *(float4*)(cb + r * 1024 + tid * 4) = v[r];    // bit-exact copy, full-line writes
        const int row = r * 8 + arow0;
        unsigned p0 = pkbf(v[r].x * nv[r].x, v[r].y * nv[r].y);
        unsigned p1 = pkbf(v[r].z * nv[r].z, v[r].w * nv[r].w);
        uint2 pp; pp.x = p0; pp.y = p1;
        *(uint2*)&hlds[row * 68 + (acol >> 1)] = pp;
    }
    // ---- stage W1 into LDS as bf16 (L2-hot global reads) ----
    {
        const int a = tid >> 2, q = tid & 3;
        const float* src = W1 + a * HID + q * 32;
        float x[32];
        #pragma unroll
        for (int i = 0; i < 8; ++i) *(float4*)&x[i * 4] = *(const float4*)(src + i * 4);
        unsigned* dst = &w1lds[a * 68 + q * 16];
        #pragma unroll
        for (int i = 0; i < 16; ++i) dst[i] = pkbf(x[2 * i], x[2 * i + 1]);
    }

    const int w    = tid >> 6;
    const int lane = tid & 63;
    const int c    = lane & 15;
    const int g    = lane >> 4;
    const float inv_scale = rsqrtf((float)nnum[0]);

    // W2 B-fragments (bf16): lane (c,g) holds B[k=ks2*32+g*8+i][col=c] = W2[c][k], c<8
    bf16x8 wf2[2];
    #pragma unroll
    for (int ks2 = 0; ks2 < 2; ++ks2) {
        union { bf16x8 vv; unsigned u[4]; } t;
        #pragma unroll
        for (int i = 0; i < 4; ++i) {
            float lo = (c < 8) ? W2[c * 64 + ks2 * 32 + g * 8 + 2 * i]     : 0.f;
            float hi = (c < 8) ? W2[c * 64 + ks2 * 32 + g * 8 + 2 * i + 1] : 0.f;
            t.u[i] = pkbf(lo, hi);
        }
        wf2[ks2] = t.vv;
    }
    float b1v[4];
    #pragma unroll
    for (int cf = 0; cf < 4; ++cf) b1v[cf] = b1[cf * 16 + c];
    const float b2v = (c < 8) ? b2[c] : 0.f;

    __syncthreads();

    // ---- phase B: s1 GEMM (16 MFMA), tanh, s2 MFMA ----
    const bf16x8* wptr = reinterpret_cast<const bf16x8*>(&w1lds[c * 68 + g * 4]);
    const bf16x8* hptr = reinterpret_cast<const bf16x8*>(&hlds[(w * 16 + c) * 68 + g * 4]);
    short* thw = thlds[w];

    bf16x8 af[4];
    #pragma unroll
    for (int ks = 0; ks < 4; ++ks) af[ks] = hptr[ks * 4];

    f32x4 acc[4];
    #pragma unroll
    for (int cf = 0; cf < 4; ++cf) acc[cf] = (f32x4){0.f, 0.f, 0.f, 0.f};
    #pragma unroll
    for (int cf = 0; cf < 4; ++cf) {
        #pragma unroll
        for (int ks = 0; ks < 4; ++ks)
            acc[cf] = __builtin_amdgcn_mfma_f32_16x16x32_bf16(af[ks], wptr[cf * 272 + ks * 4], acc[cf], 0, 0, 0);
    }
    #pragma unroll
    for (int cf = 0; cf < 4; ++cf) {
        #pragma unroll
        for (int j = 0; j < 4; ++j) {
            float th = (acc[cf][j] + b1v[cf]) * inv_scale;
            th = 1.0f - 2.0f / (__expf(2.0f * th) + 1.0f);   // tanh, inf-safe
            thw[(g * 4 + j) * 72 + cf * 16 + c] = f2bf(th);
        }
    }
    f32x4 acc2 = (f32x4){0.f, 0.f, 0.f, 0.f};
    #pragma unroll
    for (int ks2 = 0; ks2 < 2; ++ks2) {
        bf16x8 pa = *reinterpret_cast<const bf16x8*>(&thw[c * 72 + ks2 * 32 + g * 8]);
        acc2 = __builtin_amdgcn_mfma_f32_16x16x32_bf16(pa, wf2[ks2], acc2, 0, 0, 0);
    }
    if (c < 8) {
        const int rb = tile * 64 + w * 16;
        float4 o; o.x = acc2[0] + b2v; o.y = acc2[1] + b2v; o.z = acc2[2] + b2v; o.w = acc2[3] + b2v;
        *(float4*)&s2base[(size_t)c * L_ + rb + g * 4] = o;
    }
}

// ---------------- reductions helpers ----------------
__device__ __forceinline__ float waveMax(float v) {
    #pragma unroll
    for (int o = 32; o > 0; o >>= 1) v = fmaxf(v, __shfl_xor(v, o));
    return v;
}
__device__ __forceinline__ float waveSum(float v) {
    #pragma unroll
    for (int o = 32; o > 0; o >>= 1) v += __shfl_xor(v, o);
    return v;
}

// ---------------- K2: per-(b,h) softmax stats + zero aat accumulators ----------------
__global__ __launch_bounds__(256)
void k2_stats(const float* __restrict__ out, float* __restrict__ stats, float* __restrict__ aat)
{
    const int bh = blockIdx.x;                         // 0..511
    const int tid = threadIdx.x;
    if (bh == 0) {
        for (int i = tid; i < B_ * 36; i += 256) aat[i] = 0.f;
    }
    const float* row = out + OFF_A + (size_t)bh * L_;
    __shared__ float red[8];
    float m = -3.4e38f;
    for (int i = tid; i < L_; i += 256) m = fmaxf(m, row[i]);
    m = waveMax(m);
    if ((tid & 63) == 0) red[tid >> 6] = m;
    __syncthreads();
    const float M = fmaxf(fmaxf(red[0], red[1]), fmaxf(red[2], red[3]));
    float s = 0.0f;
    for (int i = tid; i < L_; i += 256) s += __expf(row[i] - M);
    s = waveSum(s);
    if ((tid & 63) == 0) red[4 + (tid >> 6)] = s;
    __syncthreads();
    if (tid == 0) {
        stats[bh * 2]     = M;
        stats[bh * 2 + 1] = red[4] + red[5] + red[6] + red[7];
    }
}

// ---------------- K3: in-place A = softmax, BW, AAT upper-tri partials (atomic) -------
__global__ __launch_bounds__(256)
void k3_soft(float* __restrict__ out, const float* __restrict__ stats, float* __restrict__ aat)
{
    const int blk = blockIdx.x;        // 256 blocks, 4 per batch
    const int b   = blk >> 2;
    const int l0  = (blk & 3) << 10;   // 1024 l's each
    const int tid = threadIdx.x;
    float* A0 = out + OFF_A + (size_t)b * HOPS * L_;
    float* BW = out + (size_t)b * L_;
    float M[HOPS], R[HOPS];
    #pragma unroll
    for (int hh = 0; hh < HOPS; ++hh) {
        M[hh] = stats[(b * HOPS + hh) * 2];
        R[hh] = 1.0f / stats[(b * HOPS + hh) * 2 + 1];
    }
    float p[36];
    #pragma unroll
    for (int i = 0; i < 36; ++i) p[i] = 0.0f;
    for (int l = l0 + tid; l < l0 + 1024; l += 256) {
        float e[HOPS]; float srow = 0.0f;
        #pragma unroll
        for (int hh = 0; hh < HOPS; ++hh) {
            float v = __expf(A0[hh * L_ + l] - M[hh]) * R[hh];
            e[hh] = v; srow += v;
        }
        #pragma unroll
        for (int hh = 0; hh < HOPS; ++hh) A0[hh * L_ + l] = e[hh];
        BW[l] = srow;
        int i = 0;
        #pragma unroll
        for (int hh = 0; hh < HOPS; ++hh) {
            #pragma unroll
            for (int gg = hh; gg < HOPS; ++gg) { p[i] = fmaf(e[hh], e[gg], p[i]); ++i; }
        }
    }
    #pragma unroll
    for (int i = 0; i < 36; ++i) p[i] = waveSum(p[i]);
    __shared__ float red[4][36];
    const int wv = tid >> 6, ln = tid & 63;
    if (ln == 0) {
        #pragma unroll
        for (int i = 0; i < 36; ++i) red[wv][i] = p[i];
    }
    __syncthreads();
    if (tid < 36) {
        float s = red[0][tid] + red[1][tid] + red[2][tid] + red[3][tid];
        atomicAdd(&aat[b * 36 + tid], s);
    }
}

// ---------------- K4: penal = sum_b sum((AAT_b - I)^2), off-diag counted twice --------
__global__ __launch_bounds__(256)
void k4_penal(const float* __restrict__ aat, float* __restrict__ out)
{
    const int tid = threadIdx.x;
    float s = 0.0f;
    for (int i = tid; i < B_ * 36; i += 256) {
        int r = i % 36;
        bool dg = (r == 0) | (r == 8) | (r == 15) | (r == 21) |
                  (r == 26) | (r == 30) | (r == 33) | (r == 35);
        float d = aat[i] - (dg ? 1.0f : 0.0f);
        float q = d * d;
        s += dg ? q : 2.0f * q;
    }
    s = waveSum(s);
    __shared__ float red[4];
    if ((tid & 63) == 0) red[tid >> 6] = s;
    __syncthreads();
    if (tid == 0) out[OFF_PENAL] = red[0] + red[1] + red[2] + red[3];
}

extern "C" void kernel_launch(void* const* d_in, const int* in_sizes, int n_in,
                              void* d_out, int out_size, void* d_ws, size_t ws_size,
                              hipStream_t stream) {
    const float* node  = (const float*)d_in[0];
    const float* neigh = (const float*)d_in[1];
    const int*   nnum  = (const int*)d_in[2];   // low 32 bits of elem 0 (LE, value in [1,64))
    const float* W1    = (const float*)d_in[3];
    const float* b1    = (const float*)d_in[4];
    const float* W2    = (const float*)d_in[5];
    const float* b2    = (const float*)d_in[6];
    float* out   = (float*)d_out;
    float* stats = (float*)d_ws;          // 512*2 floats
    float* aat   = stats + 1024;          // 64*36 floats (upper-tri, accumulated)

    k1_mfma <<<B_ * 64, 256, 0, stream>>>(node, neigh, nnum, W1, b1, W2, b2, out);
    k2_stats<<<B_ * HOPS, 256, 0, stream>>>(out, stats, aat);
    k3_soft <<<256, 256, 0, stream>>>(out, stats, aat);
    k4_penal<<<1, 256, 0, stream>>>(aat, out);
}

// Round 6
// 82.650 us; speedup vs baseline: 1.2766x; 1.2766x over previous
//
#include <hip/hip_runtime.h>
#include <hip/hip_bf16.h>
#include <math.h>

#define HID 128
#define ATT 64
#define HOPS 8
#define T_ 64
#define N_ 64
#define B_ 64
#define L_ 4096

typedef __attribute__((ext_vector_type(8))) short bf16x8;
typedef __attribute__((ext_vector_type(4))) float f32x4;

static constexpr size_t OFF_A     = (size_t)B_ * N_ * T_;              // 262144
static constexpr size_t OFF_NEIGH = OFF_A + (size_t)B_ * HOPS * L_;    // 2359296
static constexpr size_t OFF_PENAL = OFF_NEIGH + (size_t)B_ * L_ * HID; // 35913728

__device__ __forceinline__ unsigned pkbf(float lo, float hi) {
    unsigned a = (unsigned)(unsigned short)__builtin_bit_cast(unsigned short, __float2bfloat16(lo));
    unsigned b = (unsigned)(unsigned short)__builtin_bit_cast(unsigned short, __float2bfloat16(hi));
    return a | (b << 16);
}
__device__ __forceinline__ short f2bf(float x) {
    return __builtin_bit_cast(short, __float2bfloat16(x));
}

// LDS-only barrier: waits own ds_writes, does NOT drain vmcnt -> prefetch loads
// survive the barrier (T3/T4 pattern; __syncthreads would vmcnt(0)-drain).
__device__ __forceinline__ void lds_barrier() {
    asm volatile("s_waitcnt lgkmcnt(0)" ::: "memory");
    __builtin_amdgcn_s_barrier();
}

__device__ __forceinline__ void load_tile(float4 v[8], const float* nb, int tid) {
    #pragma unroll
    for (int r = 0; r < 8; ++r) v[r] = *(const float4*)(nb + r * 1024 + tid * 4);
}
__device__ __forceinline__ void store_tile(const float4 v[8], float* cb, int tid) {
    #pragma unroll
    for (int r = 0; r < 8; ++r) *(float4*)(cb + r * 1024 + tid * 4) = v[r];
}
__device__ __forceinline__ void pack_tile(const float4 v[8], const float4 nv[8],
                                          unsigned* hbuf, int tid) {
    const int arow0 = tid >> 5;
    const int acol  = (tid * 4) & 127;
    #pragma unroll
    for (int r = 0; r < 8; ++r) {
        const int row = r * 8 + arow0;
        unsigned p0 = pkbf(v[r].x * nv[r].x, v[r].y * nv[r].y);
        unsigned p1 = pkbf(v[r].z * nv[r].z, v[r].w * nv[r].w);
        uint2 pp; pp.x = p0; pp.y = p1;
        *(uint2*)&hbuf[row * 68 + (acol >> 1)] = pp;
    }
}

__device__ __forceinline__ void compute_tile(const unsigned* hbuf, const unsigned* w1l,
                                             short* thw, const bf16x8 wf2[2],
                                             const float b1v[4], float b2v, float inv_scale,
                                             float* s2base, int tile, int w, int c, int g) {
    const bf16x8* wptr = reinterpret_cast<const bf16x8*>(&w1l[c * 68 + g * 4]);
    const bf16x8* hptr = reinterpret_cast<const bf16x8*>(&hbuf[(w * 16 + c) * 68 + g * 4]);
    bf16x8 af[4];
    #pragma unroll
    for (int ks = 0; ks < 4; ++ks) af[ks] = hptr[ks * 4];
    f32x4 acc[4];
    #pragma unroll
    for (int cf = 0; cf < 4; ++cf) acc[cf] = (f32x4){0.f, 0.f, 0.f, 0.f};
    #pragma unroll
    for (int cf = 0; cf < 4; ++cf) {
        #pragma unroll
        for (int ks = 0; ks < 4; ++ks)
            acc[cf] = __builtin_amdgcn_mfma_f32_16x16x32_bf16(af[ks], wptr[cf * 272 + ks * 4], acc[cf], 0, 0, 0);
    }
    #pragma unroll
    for (int cf = 0; cf < 4; ++cf) {
        #pragma unroll
        for (int j = 0; j < 4; ++j) {
            float th = (acc[cf][j] + b1v[cf]) * inv_scale;
            th = 1.0f - 2.0f / (__expf(2.0f * th) + 1.0f);   // tanh, inf-safe
            thw[(g * 4 + j) * 72 + cf * 16 + c] = f2bf(th);
        }
    }
    f32x4 acc2 = (f32x4){0.f, 0.f, 0.f, 0.f};
    #pragma unroll
    for (int ks2 = 0; ks2 < 2; ++ks2) {
        bf16x8 pa = *reinterpret_cast<const bf16x8*>(&thw[c * 72 + ks2 * 32 + g * 8]);
        acc2 = __builtin_amdgcn_mfma_f32_16x16x32_bf16(pa, wf2[ks2], acc2, 0, 0, 0);
    }
    if (c < 8) {
        float4 o; o.x = acc2[0] + b2v; o.y = acc2[1] + b2v; o.z = acc2[2] + b2v; o.w = acc2[3] + b2v;
        *(float4*)&s2base[(size_t)c * L_ + tile * 64 + w * 16 + g * 4] = o;
    }
}

// ---------------- K1: persistent 4-tile pipeline, linear streams + MFMA ----------------
// Grid 1024; block = batch b (blockIdx>>4), tiles {q, q+16, q+32, q+48}, q=blockIdx&15.
// Double-buffered hlds + double-buffered load regs; barriers are LDS-only so prefetch
// loads stay in flight across them; copy-out stores are never waited on.
__global__ __launch_bounds__(256, 2)
void k1_mfma(const float* __restrict__ node, const float* __restrict__ neigh,
             const int* __restrict__ nnum, const float* __restrict__ W1,
             const float* __restrict__ b1, const float* __restrict__ W2,
             const float* __restrict__ b2, float* __restrict__ out)
{
    __shared__ __align__(16) unsigned w1lds[64 * 68];       // 17.0 KB
    __shared__ __align__(16) unsigned hlds[2][64 * 68];     // 34.0 KB
    __shared__ __align__(16) short    thlds[4][16 * 72];    //  9.0 KB

    const int tid = threadIdx.x;
    const int b   = blockIdx.x >> 4;
    const int q   = blockIdx.x & 15;

    const size_t bbase = (size_t)b * L_ * HID;
    const float* nb0 = neigh + bbase + (size_t)(q     ) * 64 * HID;
    const float* nb1 = neigh + bbase + (size_t)(q + 16) * 64 * HID;
    const float* nb2 = neigh + bbase + (size_t)(q + 32) * 64 * HID;
    const float* nb3 = neigh + bbase + (size_t)(q + 48) * 64 * HID;
    float* cbb = out + OFF_NEIGH + bbase;
    float* cb0 = cbb + (size_t)(q     ) * 64 * HID;
    float* cb1 = cbb + (size_t)(q + 16) * 64 * HID;
    float* cb2 = cbb + (size_t)(q + 32) * 64 * HID;
    float* cb3 = cbb + (size_t)(q + 48) * 64 * HID;
    float* s2base = out + OFF_A + (size_t)b * HOPS * L_;

    float4 va[8], vb[8], nv[8];
    load_tile(va, nb0, tid);                       // tile q in flight

    // node rows for this thread's pack lanes (loop-invariant, L2-hot)
    {
        const float* ndb = node + (size_t)b * T_ * HID;
        const int arow0 = tid >> 5;
        const int acol  = (tid * 4) & 127;
        #pragma unroll
        for (int r = 0; r < 8; ++r)
            nv[r] = *(const float4*)(ndb + (r * 8 + arow0) * HID + acol);
    }
    // stage W1 -> LDS bf16
    {
        const int a = tid >> 2, qq = tid & 3;
        const float* src = W1 + a * HID + qq * 32;
        float x[32];
        #pragma unroll
        for (int i = 0; i < 8; ++i) *(float4*)&x[i * 4] = *(const float4*)(src + i * 4);
        unsigned* dst = &w1lds[a * 68 + qq * 16];
        #pragma unroll
        for (int i = 0; i < 16; ++i) dst[i] = pkbf(x[2 * i], x[2 * i + 1]);
    }

    const int w    = tid >> 6;
    const int lane = tid & 63;
    const int c    = lane & 15;
    const int g    = lane >> 4;
    const float inv_scale = rsqrtf((float)nnum[0]);

    bf16x8 wf2[2];
    #pragma unroll
    for (int ks2 = 0; ks2 < 2; ++ks2) {
        union { bf16x8 vv; unsigned u[4]; } t;
        #pragma unroll
        for (int i = 0; i < 4; ++i) {
            float lo = (c < 8) ? W2[c * 64 + ks2 * 32 + g * 8 + 2 * i]     : 0.f;
            float hi = (c < 8) ? W2[c * 64 + ks2 * 32 + g * 8 + 2 * i + 1] : 0.f;
            t.u[i] = pkbf(lo, hi);
        }
        wf2[ks2] = t.vv;
    }
    float b1v[4];
    #pragma unroll
    for (int cf = 0; cf < 4; ++cf) b1v[cf] = b1[cf * 16 + c];
    const float b2v = (c < 8) ? b2[c] : 0.f;
    short* thw = thlds[w];

    // prologue: pack tile q, launch tile q+16, copy-out tile q
    pack_tile(va, nv, hlds[0], tid);               // waits va (vmcnt), ds_writes
    load_tile(vb, nb1, tid);                       // tile q+16 in flight
    store_tile(va, cb0, tid);
    lds_barrier();                                  // covers W1 + hlds[0] writes

    // iter 0: compute q | pack q+16 | launch q+32 | store q+16
    compute_tile(hlds[0], w1lds, thw, wf2, b1v, b2v, inv_scale, s2base, q,      w, c, g);
    pack_tile(vb, nv, hlds[1], tid);
    load_tile(va, nb2, tid);
    store_tile(vb, cb1, tid);
    lds_barrier();

    // iter 1
    compute_tile(hlds[1], w1lds, thw, wf2, b1v, b2v, inv_scale, s2base, q + 16, w, c, g);
    pack_tile(va, nv, hlds[0], tid);
    load_tile(vb, nb3, tid);
    store_tile(va, cb2, tid);
    lds_barrier();

    // iter 2
    compute_tile(hlds[0], w1lds, thw, wf2, b1v, b2v, inv_scale, s2base, q + 32, w, c, g);
    pack_tile(vb, nv, hlds[1], tid);
    store_tile(vb, cb3, tid);
    lds_barrier();

    // iter 3
    compute_tile(hlds[1], w1lds, thw, wf2, b1v, b2v, inv_scale, s2base, q + 48, w, c, g);
}

// ---------------- reductions helpers ----------------
__device__ __forceinline__ float waveMax(float v) {
    #pragma unroll
    for (int o = 32; o > 0; o >>= 1) v = fmaxf(v, __shfl_xor(v, o));
    return v;
}
__device__ __forceinline__ float waveSum(float v) {
    #pragma unroll
    for (int o = 32; o > 0; o >>= 1) v += __shfl_xor(v, o);
    return v;
}

// ---------------- K2: per-(b,h) softmax stats + zero aat accumulators ----------------
__global__ __launch_bounds__(256)
void k2_stats(const float* __restrict__ out, float* __restrict__ stats, float* __restrict__ aat)
{
    const int bh = blockIdx.x;                         // 0..511
    const int tid = threadIdx.x;
    if (bh == 0) {
        for (int i = tid; i < B_ * 36; i += 256) aat[i] = 0.f;
    }
    const float* row = out + OFF_A + (size_t)bh * L_;
    __shared__ float red[8];
    float m = -3.4e38f;
    for (int i = tid; i < L_; i += 256) m = fmaxf(m, row[i]);
    m = waveMax(m);
    if ((tid & 63) == 0) red[tid >> 6] = m;
    __syncthreads();
    const float M = fmaxf(fmaxf(red[0], red[1]), fmaxf(red[2], red[3]));
    float s = 0.0f;
    for (int i = tid; i < L_; i += 256) s += __expf(row[i] - M);
    s = waveSum(s);
    if ((tid & 63) == 0) red[4 + (tid >> 6)] = s;
    __syncthreads();
    if (tid == 0) {
        stats[bh * 2]     = M;
        stats[bh * 2 + 1] = red[4] + red[5] + red[6] + red[7];
    }
}

// ---------------- K3: in-place A = softmax, BW, AAT upper-tri partials (atomic) -------
__global__ __launch_bounds__(256)
void k3_soft(float* __restrict__ out, const float* __restrict__ stats, float* __restrict__ aat)
{
    const int blk = blockIdx.x;        // 256 blocks, 4 per batch
    const int b   = blk >> 2;
    const int l0  = (blk & 3) << 10;   // 1024 l's each
    const int tid = threadIdx.x;
    float* A0 = out + OFF_A + (size_t)b * HOPS * L_;
    float* BW = out + (size_t)b * L_;
    float M[HOPS], R[HOPS];
    #pragma unroll
    for (int hh = 0; hh < HOPS; ++hh) {
        M[hh] = stats[(b * HOPS + hh) * 2];
        R[hh] = 1.0f / stats[(b * HOPS + hh) * 2 + 1];
    }
    float p[36];
    #pragma unroll
    for (int i = 0; i < 36; ++i) p[i] = 0.0f;
    for (int l = l0 + tid; l < l0 + 1024; l += 256) {
        float e[HOPS]; float srow = 0.0f;
        #pragma unroll
        for (int hh = 0; hh < HOPS; ++hh) {
            float v = __expf(A0[hh * L_ + l] - M[hh]) * R[hh];
            e[hh] = v; srow += v;
        }
        #pragma unroll
        for (int hh = 0; hh < HOPS; ++hh) A0[hh * L_ + l] = e[hh];
        BW[l] = srow;
        int i = 0;
        #pragma unroll
        for (int hh = 0; hh < HOPS; ++hh) {
            #pragma unroll
            for (int gg = hh; gg < HOPS; ++gg) { p[i] = fmaf(e[hh], e[gg], p[i]); ++i; }
        }
    }
    #pragma unroll
    for (int i = 0; i < 36; ++i) p[i] = waveSum(p[i]);
    __shared__ float red[4][36];
    const int wv = tid >> 6, ln = tid & 63;
    if (ln == 0) {
        #pragma unroll
        for (int i = 0; i < 36; ++i) red[wv][i] = p[i];
    }
    __syncthreads();
    if (tid < 36) {
        float s = red[0][tid] + red[1][tid] + red[2][tid] + red[3][tid];
        atomicAdd(&aat[b * 36 + tid], s);
    }
}

// ---------------- K4: penal = sum_b sum((AAT_b - I)^2), off-diag counted twice --------
__global__ __launch_bounds__(256)
void k4_penal(const float* __restrict__ aat, float* __restrict__ out)
{
    const int tid = threadIdx.x;
    float s = 0.0f;
    for (int i = tid; i < B_ * 36; i += 256) {
        int r = i % 36;
        bool dg = (r == 0) | (r == 8) | (r == 15) | (r == 21) |
                  (r == 26) | (r == 30) | (r == 33) | (r == 35);
        float d = aat[i] - (dg ? 1.0f : 0.0f);
        float q = d * d;
        s += dg ? q : 2.0f * q;
    }
    s = waveSum(s);
    __shared__ float red[4];
    if ((tid & 63) == 0) red[tid >> 6] = s;
    __syncthreads();
    if (tid == 0) out[OFF_PENAL] = red[0] + red[1] + red[2] + red[3];
}

extern "C" void kernel_launch(void* const* d_in, const int* in_sizes, int n_in,
                              void* d_out, int out_size, void* d_ws, size_t ws_size,
                              hipStream_t stream) {
    const float* node  = (const float*)d_in[0];
    const float* neigh = (const float*)d_in[1];
    const int*   nnum  = (const int*)d_in[2];   // low 32 bits of elem 0 (LE, value in [1,64))
    const float* W1    = (const float*)d_in[3];
    const float* b1    = (const float*)d_in[4];
    const float* W2    = (const float*)d_in[5];
    const float* b2    = (const float*)d_in[6];
    float* out   = (float*)d_out;
    float* stats = (float*)d_ws;          // 512*2 floats
    float* aat   = stats + 1024;          // 64*36 floats (upper-tri, accumulated)

    k1_mfma <<<B_ * 16, 256, 0, stream>>>(node, neigh, nnum, W1, b1, W2, b2, out);
    k2_stats<<<B_ * HOPS, 256, 0, stream>>>(out, stats, aat);
    k3_soft <<<256, 256, 0, stream>>>(out, stats, aat);
    k4_penal<<<1, 256, 0, stream>>>(aat, out);
}